// Round 1
// baseline (1411.412 us; speedup 1.0000x reference)
//
#include <hip/hip_runtime.h>
#include <hip/hip_bf16.h>

// C[m,n] = sum_{r,k} A[r][m][k] * B[r][n][k]
//   A: [8, 8192, 1024] fp32   B: [8, 4096, 1024] fp32   C: [8192, 4096] fp32
// Single-GEMM view: C = A' * B'^T, M=8192, N=4096, K=8192 (8 panels of 1024).
// Strategy: fused fp32->bf16 conversion while reg-staging into LDS,
// mfma_f32_16x16x32_bf16, 128x128 tile, BK=32, 4 waves (2x2 of 64x64).

#define M_TOT 8192
#define N_TOT 4096
#define LK    1024
#define NR    8
#define K_TOT (NR * LK)

#define BM 128
#define BN 128
#define BK 32
#define PAD_ROW 40   // shorts per LDS row = 80 B (32 data + 8 pad) -> 2-way banks only

typedef float f32x4 __attribute__((ext_vector_type(4)));
typedef short s16x8 __attribute__((ext_vector_type(8)));

__device__ inline short f2bf(float f) {
    __hip_bfloat16 h = __float2bfloat16(f);
    return *reinterpret_cast<short*>(&h);
}

__global__ __launch_bounds__(256, 2)
void gemm_rs_fused(const float* __restrict__ A, const float* __restrict__ B,
                   float* __restrict__ C) {
    __shared__ short lA[BM * PAD_ROW];
    __shared__ short lB[BN * PAD_ROW];

    // XCD-aware bijective swizzle: 2048 blocks, 8 XCDs, 256 per XCD.
    const int bid = blockIdx.x;
    const int sw  = (bid & 7) * (int)(gridDim.x >> 3) + (bid >> 3);
    const int bm  = sw >> 5;   // 64 row-blocks
    const int bn  = sw & 31;   // 32 col-blocks

    const int tid  = threadIdx.x;
    const int lane = tid & 63;
    const int wid  = tid >> 6;
    const int wr   = wid >> 1;   // wave row 0..1
    const int wc   = wid & 1;    // wave col 0..1
    const int r15  = lane & 15;
    const int kg   = lane >> 4;  // 0..3

    // staging: each thread loads 16 consecutive fp32 of one tile-row
    const int srow = tid >> 1;   // 0..127
    const int scg  = tid & 1;    // 16-element group within the 32-wide row

    const float* gA = A + ((size_t)(bm * BM + srow) << 10) + scg * 16;
    const float* gB = B + ((size_t)(bn * BN + srow) << 10) + scg * 16;

    short* wpA = lA + srow * PAD_ROW + scg * 16;
    short* wpB = lB + srow * PAD_ROW + scg * 16;

    const short* rpA = lA + (wr * 64 + r15) * PAD_ROW + kg * 8;
    const short* rpB = lB + (wc * 64 + r15) * PAD_ROW + kg * 8;

    f32x4 acc[4][4];
    #pragma unroll
    for (int i = 0; i < 4; ++i)
        #pragma unroll
        for (int j = 0; j < 4; ++j)
            acc[i][j] = (f32x4){0.f, 0.f, 0.f, 0.f};

    for (int t = 0; t < K_TOT / BK; ++t) {
        const int r  = t >> 5;           // panel index (t*32 / 1024)
        const int k0 = (t & 31) << 5;    // offset within panel
        const float* pA = gA + (size_t)r * (M_TOT * LK) + k0;
        const float* pB = gB + (size_t)r * (N_TOT * LK) + k0;

        f32x4 va[4], vb[4];
        #pragma unroll
        for (int q = 0; q < 4; ++q) va[q] = *(const f32x4*)(pA + q * 4);
        #pragma unroll
        for (int q = 0; q < 4; ++q) vb[q] = *(const f32x4*)(pB + q * 4);

        __syncthreads();   // previous iteration's LDS reads complete

        s16x8 oa0, oa1, ob0, ob1;
        #pragma unroll
        for (int q = 0; q < 2; ++q)
            #pragma unroll
            for (int i = 0; i < 4; ++i) {
                oa0[q * 4 + i] = f2bf(va[q][i]);
                oa1[q * 4 + i] = f2bf(va[q + 2][i]);
                ob0[q * 4 + i] = f2bf(vb[q][i]);
                ob1[q * 4 + i] = f2bf(vb[q + 2][i]);
            }
        *(s16x8*)(wpA)     = oa0;
        *(s16x8*)(wpA + 8) = oa1;
        *(s16x8*)(wpB)     = ob0;
        *(s16x8*)(wpB + 8) = ob1;

        __syncthreads();

        s16x8 af[4], bf[4];
        #pragma unroll
        for (int i = 0; i < 4; ++i) af[i] = *(const s16x8*)(rpA + i * 16 * PAD_ROW);
        #pragma unroll
        for (int i = 0; i < 4; ++i) bf[i] = *(const s16x8*)(rpB + i * 16 * PAD_ROW);

        #pragma unroll
        for (int i = 0; i < 4; ++i)
            #pragma unroll
            for (int j = 0; j < 4; ++j)
                acc[i][j] = __builtin_amdgcn_mfma_f32_16x16x32_bf16(
                    af[i], bf[j], acc[i][j], 0, 0, 0);
    }

    // Epilogue: C/D layout col=lane&15, row=(lane>>4)*4+j  [m89-verified]
    float* Cp = C + (size_t)(bm * BM + wr * 64 + kg * 4) * N_TOT
                  + bn * BN + wc * 64 + r15;
    #pragma unroll
    for (int i = 0; i < 4; ++i)
        #pragma unroll
        for (int j = 0; j < 4; ++j)
            #pragma unroll
            for (int jj = 0; jj < 4; ++jj)
                Cp[(size_t)(i * 16 + jj) * N_TOT + j * 16] = acc[i][j][jj];
}

extern "C" void kernel_launch(void* const* d_in, const int* in_sizes, int n_in,
                              void* d_out, int out_size, void* d_ws, size_t ws_size,
                              hipStream_t stream) {
    const float* A = (const float*)d_in[0];   // [8, 8192, 1024]
    const float* B = (const float*)d_in[1];   // [8, 4096, 1024]
    float* C = (float*)d_out;                 // [8192, 4096]
    gemm_rs_fused<<<dim3((M_TOT / BM) * (N_TOT / BN)), dim3(256), 0, stream>>>(A, B, C);
}

// Round 2
// 899.973 us; speedup vs baseline: 1.5683x; 1.5683x over previous
//
#include <hip/hip_runtime.h>
#include <hip/hip_bf16.h>

// C[m,n] = sum_{r,k} A[r][m][k] * B[r][n][k]
//   A: [8, 8192, 1024] fp32   B: [8, 4096, 1024] fp32   C: [8192, 4096] fp32
// Plan: (1) convert A,B -> bf16 in d_ws with K made contiguous (k' = r*1024+k),
//       (2) m97-structure bf16 GEMM: 128x128 tile, BK=32, global_load_lds(16B),
//           4 waves, linear LDS, 2 barriers/K-step, XCD-bijective swizzle.

#define M_TOT 8192
#define N_TOT 4096
#define LK    1024
#define NR    8
#define K_TOT (NR * LK)   // 8192

typedef float f32x4 __attribute__((ext_vector_type(4)));
typedef short s16x8 __attribute__((ext_vector_type(8)));

typedef const __attribute__((address_space(1))) unsigned int* gptr_t;
typedef __attribute__((address_space(3))) unsigned int* lptr_t;

__device__ inline short f2bf(float f) {
    __hip_bfloat16 h = __float2bfloat16(f);
    return *reinterpret_cast<short*>(&h);
}

// ---------------- convert pre-pass ----------------
// in:  [nrows][1024] fp32 rows, row = r*(rows_per_panel... actually flat panels)
//      flat row index `row` decomposes as r = row >> row_shift, m = row & row_mask
// out: bf16 [m][K_TOT] with out col = r*1024 + c
__global__ __launch_bounds__(256)
void cvt_bf16(const float* __restrict__ in, short* __restrict__ out,
              int row_shift, int row_mask) {
    const int row = blockIdx.x * 2 + (threadIdx.x >> 7);
    const int c   = (threadIdx.x & 127) * 8;
    const int r   = row >> row_shift;
    const int m   = row & row_mask;
    const float* src = in + ((size_t)row << 10) + c;
    f32x4 v0 = *(const f32x4*)src;
    f32x4 v1 = *(const f32x4*)(src + 4);
    s16x8 o;
    #pragma unroll
    for (int j = 0; j < 4; ++j) { o[j] = f2bf(v0[j]); o[j + 4] = f2bf(v1[j]); }
    *(s16x8*)(out + ((size_t)m << 13) + ((size_t)r << 10) + c) = o;
}

// ---------------- bf16 GEMM (m97 structure) ----------------
__global__ __launch_bounds__(256, 2)
void gemm_bf16(const short* __restrict__ A, const short* __restrict__ B,
               float* __restrict__ C) {
    __shared__ short lA[128 * 32];
    __shared__ short lB[128 * 32];

    const int bid = blockIdx.x;
    const int sw  = (bid & 7) * (int)(gridDim.x >> 3) + (bid >> 3);  // 2048 % 8 == 0
    const int bm  = sw >> 5;   // 64 row-blocks
    const int bn  = sw & 31;   // 32 col-blocks

    const int tid  = threadIdx.x;
    const int lane = tid & 63;
    const int wid  = tid >> 6;
    const int wr   = wid >> 1;
    const int wc   = wid & 1;
    const int r15  = lane & 15;
    const int kg   = lane >> 4;

    // staging: wave wid stages rows [wid*32, wid*32+32) in 2 calls of 16 rows
    const int srow = wid * 32 + (lane >> 2);
    const int scol = (lane & 3) * 8;
    const short* gA = A + (size_t)(bm * 128 + srow) * K_TOT + scol;
    const short* gB = B + (size_t)(bn * 128 + srow) * K_TOT + scol;
    short* lwA = lA + (wid * 32) * 32;   // wave-uniform LDS bases
    short* lwB = lB + (wid * 32) * 32;

    const short* rpA = lA + (wr * 64 + r15) * 32 + kg * 8;
    const short* rpB = lB + (wc * 64 + r15) * 32 + kg * 8;

    f32x4 acc[4][4];
    #pragma unroll
    for (int i = 0; i < 4; ++i)
        #pragma unroll
        for (int j = 0; j < 4; ++j)
            acc[i][j] = (f32x4){0.f, 0.f, 0.f, 0.f};

    for (int t = 0; t < K_TOT / 32; ++t) {
        const short* pA = gA + t * 32;
        const short* pB = gB + t * 32;

        __syncthreads();   // previous iteration's ds_reads complete before overwrite
        __builtin_amdgcn_global_load_lds((gptr_t)pA, (lptr_t)lwA, 16, 0, 0);
        __builtin_amdgcn_global_load_lds((gptr_t)(pA + 16 * K_TOT),
                                         (lptr_t)(lwA + 16 * 32), 16, 0, 0);
        __builtin_amdgcn_global_load_lds((gptr_t)pB, (lptr_t)lwB, 16, 0, 0);
        __builtin_amdgcn_global_load_lds((gptr_t)(pB + 16 * K_TOT),
                                         (lptr_t)(lwB + 16 * 32), 16, 0, 0);
        __syncthreads();   // compiler emits vmcnt(0) drain before barrier

        s16x8 af[4], bfr[4];
        #pragma unroll
        for (int i = 0; i < 4; ++i) af[i]  = *(const s16x8*)(rpA + i * 16 * 32);
        #pragma unroll
        for (int i = 0; i < 4; ++i) bfr[i] = *(const s16x8*)(rpB + i * 16 * 32);

        #pragma unroll
        for (int i = 0; i < 4; ++i)
            #pragma unroll
            for (int j = 0; j < 4; ++j)
                acc[i][j] = __builtin_amdgcn_mfma_f32_16x16x32_bf16(
                    af[i], bfr[j], acc[i][j], 0, 0, 0);
    }

    float* Cp = C + (size_t)(bm * 128 + wr * 64 + kg * 4) * N_TOT
                  + bn * 128 + wc * 64 + r15;
    #pragma unroll
    for (int i = 0; i < 4; ++i)
        #pragma unroll
        for (int j = 0; j < 4; ++j)
            #pragma unroll
            for (int jj = 0; jj < 4; ++jj)
                Cp[(size_t)(i * 16 + jj) * N_TOT + j * 16] = acc[i][j][jj];
}

// ---------------- fallback (round-1 fused kernel, used only if ws too small) ----------------
#define PAD_ROW 40
__global__ __launch_bounds__(256, 2)
void gemm_rs_fused(const float* __restrict__ A, const float* __restrict__ B,
                   float* __restrict__ C) {
    __shared__ short lA[128 * PAD_ROW];
    __shared__ short lB[128 * PAD_ROW];
    const int bid = blockIdx.x;
    const int sw  = (bid & 7) * (int)(gridDim.x >> 3) + (bid >> 3);
    const int bm = sw >> 5, bn = sw & 31;
    const int tid = threadIdx.x, lane = tid & 63, wid = tid >> 6;
    const int wr = wid >> 1, wc = wid & 1, r15 = lane & 15, kg = lane >> 4;
    const int srow = tid >> 1, scg = tid & 1;
    const float* gA = A + ((size_t)(bm * 128 + srow) << 10) + scg * 16;
    const float* gB = B + ((size_t)(bn * 128 + srow) << 10) + scg * 16;
    short* wpA = lA + srow * PAD_ROW + scg * 16;
    short* wpB = lB + srow * PAD_ROW + scg * 16;
    const short* rpA = lA + (wr * 64 + r15) * PAD_ROW + kg * 8;
    const short* rpB = lB + (wc * 64 + r15) * PAD_ROW + kg * 8;
    f32x4 acc[4][4];
    #pragma unroll
    for (int i = 0; i < 4; ++i)
        #pragma unroll
        for (int j = 0; j < 4; ++j) acc[i][j] = (f32x4){0.f, 0.f, 0.f, 0.f};
    for (int t = 0; t < K_TOT / 32; ++t) {
        const int r = t >> 5, k0 = (t & 31) << 5;
        const float* pA = gA + (size_t)r * (M_TOT * LK) + k0;
        const float* pB = gB + (size_t)r * (N_TOT * LK) + k0;
        f32x4 va[4], vb[4];
        #pragma unroll
        for (int q = 0; q < 4; ++q) va[q] = *(const f32x4*)(pA + q * 4);
        #pragma unroll
        for (int q = 0; q < 4; ++q) vb[q] = *(const f32x4*)(pB + q * 4);
        __syncthreads();
        s16x8 oa0, oa1, ob0, ob1;
        #pragma unroll
        for (int q = 0; q < 2; ++q)
            #pragma unroll
            for (int i = 0; i < 4; ++i) {
                oa0[q * 4 + i] = f2bf(va[q][i]);
                oa1[q * 4 + i] = f2bf(va[q + 2][i]);
                ob0[q * 4 + i] = f2bf(vb[q][i]);
                ob1[q * 4 + i] = f2bf(vb[q + 2][i]);
            }
        *(s16x8*)(wpA) = oa0; *(s16x8*)(wpA + 8) = oa1;
        *(s16x8*)(wpB) = ob0; *(s16x8*)(wpB + 8) = ob1;
        __syncthreads();
        s16x8 af[4], bfr[4];
        #pragma unroll
        for (int i = 0; i < 4; ++i) af[i]  = *(const s16x8*)(rpA + i * 16 * PAD_ROW);
        #pragma unroll
        for (int i = 0; i < 4; ++i) bfr[i] = *(const s16x8*)(rpB + i * 16 * PAD_ROW);
        #pragma unroll
        for (int i = 0; i < 4; ++i)
            #pragma unroll
            for (int j = 0; j < 4; ++j)
                acc[i][j] = __builtin_amdgcn_mfma_f32_16x16x32_bf16(
                    af[i], bfr[j], acc[i][j], 0, 0, 0);
    }
    float* Cp = C + (size_t)(bm * 128 + wr * 64 + kg * 4) * N_TOT
                  + bn * 128 + wc * 64 + r15;
    #pragma unroll
    for (int i = 0; i < 4; ++i)
        #pragma unroll
        for (int j = 0; j < 4; ++j)
            #pragma unroll
            for (int jj = 0; jj < 4; ++jj)
                Cp[(size_t)(i * 16 + jj) * N_TOT + j * 16] = acc[i][j][jj];
}

extern "C" void kernel_launch(void* const* d_in, const int* in_sizes, int n_in,
                              void* d_out, int out_size, void* d_ws, size_t ws_size,
                              hipStream_t stream) {
    const float* A = (const float*)d_in[0];   // [8, 8192, 1024]
    const float* B = (const float*)d_in[1];   // [8, 4096, 1024]
    float* C = (float*)d_out;                 // [8192, 4096]

    const size_t needA = (size_t)M_TOT * K_TOT * 2;   // 134,217,728 B
    const size_t needB = (size_t)N_TOT * K_TOT * 2;   //  67,108,864 B

    if (ws_size >= needA + needB) {
        short* Abf = (short*)d_ws;
        short* Bbf = (short*)((char*)d_ws + needA);
        // A: 65536 rows of 1024; row = r*8192 + m  -> shift 13, mask 8191
        cvt_bf16<<<dim3(NR * M_TOT / 2), dim3(256), 0, stream>>>(A, Abf, 13, 8191);
        // B: 32768 rows of 1024; row = r*4096 + n  -> shift 12, mask 4095
        cvt_bf16<<<dim3(NR * N_TOT / 2), dim3(256), 0, stream>>>(B, Bbf, 12, 4095);
        gemm_bf16<<<dim3((M_TOT / 128) * (N_TOT / 128)), dim3(256), 0, stream>>>(Abf, Bbf, C);
    } else {
        gemm_rs_fused<<<dim3((M_TOT / 128) * (N_TOT / 128)), dim3(256), 0, stream>>>(A, B, C);
    }
}

// Round 3
// 544.627 us; speedup vs baseline: 2.5915x; 1.6525x over previous
//
#include <hip/hip_runtime.h>
#include <hip/hip_bf16.h>

// C[m,n] = sum_{r,k} A[r][m][k] * B[r][n][k]
// Phase 1: convert A,B -> bf16 in d_ws (K contiguous: k' = r*1024+k).
// Phase 2: 256x256 8-phase bf16 GEMM (T2 swizzle + T3/T4 counted vmcnt + T5 setprio).

#define M_TOT 8192
#define N_TOT 4096
#define LK    1024
#define NR    8
#define K_TOT (NR * LK)   // 8192
#define NT    (K_TOT / 64) // 128 K-tiles

typedef float f32x4 __attribute__((ext_vector_type(4)));
typedef short s16x8 __attribute__((ext_vector_type(8)));
typedef const __attribute__((address_space(1))) unsigned int* gptr_t;
typedef __attribute__((address_space(3))) unsigned int* lptr_t;

__device__ inline short f2bf(float f) {
    __hip_bfloat16 h = __float2bfloat16(f);
    return *reinterpret_cast<short*>(&h);
}

// ---------------- convert pre-pass (unchanged, ~95us @ ~6 TB/s) ----------------
__global__ __launch_bounds__(256)
void cvt_bf16(const float* __restrict__ in, short* __restrict__ out,
              int row_shift, int row_mask) {
    const int row = blockIdx.x * 2 + (threadIdx.x >> 7);
    const int c   = (threadIdx.x & 127) * 8;
    const int r   = row >> row_shift;
    const int m   = row & row_mask;
    const float* src = in + ((size_t)row << 10) + c;
    f32x4 v0 = *(const f32x4*)src;
    f32x4 v1 = *(const f32x4*)(src + 4);
    s16x8 o;
    #pragma unroll
    for (int j = 0; j < 4; ++j) { o[j] = f2bf(v0[j]); o[j + 4] = f2bf(v1[j]); }
    *(s16x8*)(out + ((size_t)m << 13) + ((size_t)r << 10) + c) = o;
}

// ---------------- 8-phase 256^2 GEMM ----------------
// LDS (shorts): buf c at c*32768; A-tile [256][64] at +0, B-tile at +16384.
// Swizzle: 16B granule g at row r holds global granule g ^ (r&7).
//   write side: gload_lds linear dest (base+lane*16); lane l -> row r0+(l>>3),
//               granule l&7; so src granule = (l&7)^(l>>3)  (r0 % 8 == 0).
//   read side:  off_shorts = row*64 + ((gl ^ (row&7)) << 3).

__device__ __forceinline__ void stage_half(const short* srcBase, short* ldsOp,
                                           int half, int ktile, int wid) {
    #pragma unroll
    for (int q = 0; q < 2; ++q) {
        const short* src = srcBase + (size_t)(half * 128 + q * 8) * K_TOT + ktile * 64;
        short* dst = ldsOp + (half * 128 + wid * 16 + q * 8) * 64;  // wave-uniform
        __builtin_amdgcn_global_load_lds((gptr_t)src, (lptr_t)dst, 16, 0, 0);
    }
}

template<int F0>
__device__ __forceinline__ void read_a2(s16x8 (&afr)[8][2], const short* lAc,
                                        int wm, int r15, int kg) {
    #pragma unroll
    for (int fo = 0; fo < 2; ++fo)
        #pragma unroll
        for (int ks = 0; ks < 2; ++ks) {
            const int row = wm * 128 + (F0 + fo) * 16 + r15;
            const int off = row * 64 + ((((ks << 2) | kg) ^ (row & 7)) << 3);
            afr[F0 + fo][ks] = *(const s16x8*)(lAc + off);
        }
}

__device__ __forceinline__ void read_b(s16x8 (&bfr)[4][2], const short* lBc,
                                       int wn, int r15, int kg) {
    #pragma unroll
    for (int n = 0; n < 4; ++n)
        #pragma unroll
        for (int ks = 0; ks < 2; ++ks) {
            const int row = wn * 64 + n * 16 + r15;
            const int off = row * 64 + ((((ks << 2) | kg) ^ (row & 7)) << 3);
            bfr[n][ks] = *(const s16x8*)(lBc + off);
        }
}

template<int Q>
__device__ __forceinline__ void mfma_quad(f32x4 (&acc)[8][4], s16x8 (&afr)[8][2],
                                          s16x8 (&bfr)[4][2]) {
    __builtin_amdgcn_s_setprio(1);
    #pragma unroll
    for (int fo = 0; fo < 2; ++fo)
        #pragma unroll
        for (int n = 0; n < 4; ++n)
            #pragma unroll
            for (int ks = 0; ks < 2; ++ks)
                acc[Q * 2 + fo][n] = __builtin_amdgcn_mfma_f32_16x16x32_bf16(
                    afr[Q * 2 + fo][ks], bfr[n][ks], acc[Q * 2 + fo][n], 0, 0, 0);
    __builtin_amdgcn_s_setprio(0);
}

#define PHASE_SYNC() do { \
    asm volatile("" ::: "memory"); \
    __builtin_amdgcn_s_barrier(); \
    asm volatile("s_waitcnt lgkmcnt(0)" ::: "memory"); \
    __builtin_amdgcn_sched_barrier(0); } while (0)

#define PHASE_END() do { \
    asm volatile("" ::: "memory"); \
    __builtin_amdgcn_s_barrier(); } while (0)

__global__ __launch_bounds__(512, 2)
void gemm8(const short* __restrict__ A, const short* __restrict__ B,
           float* __restrict__ C) {
    extern __shared__ short smem[];

    const int tid  = threadIdx.x;
    const int lane = tid & 63;
    const int wid  = tid >> 6;
    const int wm   = wid >> 2;     // 0..1
    const int wn   = wid & 3;      // 0..3
    const int r15  = lane & 15;
    const int kg   = lane >> 4;
    const int l8   = lane >> 3;           // 0..7
    const int g16  = (lane & 7) ^ l8;     // pre-swizzled source granule

    const int bid = blockIdx.x;
    const int sw  = (bid & 7) * 64 + (bid >> 3);   // 512 % 8 == 0, bijective
    const int bm  = sw >> 4;   // 0..31
    const int bn  = sw & 15;   // 0..15

    // per-thread staging source bases (row = +wid*16+l8, col granule = g16)
    const short* srcA = A + (size_t)(bm * 256 + wid * 16 + l8) * K_TOT + g16 * 8;
    const short* srcB = B + (size_t)(bn * 256 + wid * 16 + l8) * K_TOT + g16 * 8;

    short* b0A = smem;
    short* b0B = smem + 16384;
    short* b1A = smem + 32768;
    short* b1B = smem + 49152;

    // Prologue: 7 half-tiles (tile0: B0,B1,A0,A1 -> buf0; tile1: B0,B1,A0 -> buf1)
    stage_half(srcB, b0B, 0, 0, wid);
    stage_half(srcB, b0B, 1, 0, wid);
    stage_half(srcA, b0A, 0, 0, wid);
    stage_half(srcA, b0A, 1, 0, wid);
    stage_half(srcB, b1B, 0, 1, wid);
    stage_half(srcB, b1B, 1, 1, wid);
    stage_half(srcA, b1A, 0, 1, wid);
    asm volatile("s_waitcnt vmcnt(6)" ::: "memory");  // tile0's 8 loads complete
    asm volatile("" ::: "memory");
    __builtin_amdgcn_s_barrier();

    f32x4 acc[8][4];
    #pragma unroll
    for (int f = 0; f < 8; ++f)
        #pragma unroll
        for (int n = 0; n < 4; ++n)
            acc[f][n] = (f32x4){0.f, 0.f, 0.f, 0.f};

    s16x8 afr[8][2];
    s16x8 bfr[4][2];

    for (int t = 0; t < NT; ++t) {
        const int cur = t & 1;
        const short* lAc = smem + (cur << 15);
        const short* lBc = lAc + 16384;
        short* sA_nx  = smem + ((cur ^ 1) << 15);           // A of tile t+1
        short* sA_nx2 = smem + (cur << 15);                 // A of tile t+2
        short* sB_nx2 = sA_nx2 + 16384;                     // B of tile t+2

        // ---- phase 1: read B (8) + A-quad0 (4); stage A1 of t+1 (other buf)
        read_b(bfr, lBc, wn, r15, kg);
        read_a2<0>(afr, lAc, wm, r15, kg);
        if (t + 1 < NT) stage_half(srcA, sA_nx, 1, t + 1, wid);
        PHASE_SYNC();
        mfma_quad<0>(acc, afr, bfr);
        PHASE_END();

        // ---- phase 2: read A-quad1; stage B0 of t+2 (B fully read in p1)
        read_a2<2>(afr, lAc, wm, r15, kg);
        if (t + 2 < NT) stage_half(srcB, sB_nx2, 0, t + 2, wid);
        PHASE_SYNC();
        mfma_quad<1>(acc, afr, bfr);
        PHASE_END();

        // ---- phase 3: read A-quad2+quad3; stage B1 of t+2
        read_a2<4>(afr, lAc, wm, r15, kg);
        read_a2<6>(afr, lAc, wm, r15, kg);
        if (t + 2 < NT) stage_half(srcB, sB_nx2, 1, t + 2, wid);
        PHASE_SYNC();
        mfma_quad<2>(acc, afr, bfr);
        PHASE_END();

        // ---- phase 4: stage A0 of t+2 (all A reads done by p3's lgkmcnt);
        //      counted vmcnt: newest 6 loads (B0,B1,A0 of t+2) may stay in flight
        if (t + 2 < NT) stage_half(srcA, sA_nx2, 0, t + 2, wid);
        if (t < NT - 2)       { asm volatile("s_waitcnt vmcnt(6)" ::: "memory"); }
        else if (t == NT - 2) { asm volatile("s_waitcnt vmcnt(0)" ::: "memory"); }
        PHASE_SYNC();
        mfma_quad<3>(acc, afr, bfr);
        PHASE_END();
    }

    // Epilogue: C/D layout col=lane&15, row=(lane>>4)*4+jj  [m89-verified]
    float* Cp = C + (size_t)(bm * 256 + wm * 128 + kg * 4) * N_TOT
                  + bn * 256 + wn * 64 + r15;
    #pragma unroll
    for (int f = 0; f < 8; ++f)
        #pragma unroll
        for (int n = 0; n < 4; ++n)
            #pragma unroll
            for (int jj = 0; jj < 4; ++jj)
                Cp[(size_t)(f * 16 + jj) * N_TOT + n * 16] = acc[f][n][jj];
}

// ---------------- fallback (round-1 fused kernel, only if ws too small) ----------------
#define PAD_ROW 40
__global__ __launch_bounds__(256, 2)
void gemm_rs_fused(const float* __restrict__ A, const float* __restrict__ B,
                   float* __restrict__ C) {
    __shared__ short lA[128 * PAD_ROW];
    __shared__ short lB[128 * PAD_ROW];
    const int bid = blockIdx.x;
    const int sw  = (bid & 7) * (int)(gridDim.x >> 3) + (bid >> 3);
    const int bm = sw >> 5, bn = sw & 31;
    const int tid = threadIdx.x, lane = tid & 63, wid = tid >> 6;
    const int wr = wid >> 1, wc = wid & 1, r15 = lane & 15, kg = lane >> 4;
    const int srow = tid >> 1, scg = tid & 1;
    const float* gA = A + ((size_t)(bm * 128 + srow) << 10) + scg * 16;
    const float* gB = B + ((size_t)(bn * 128 + srow) << 10) + scg * 16;
    short* wpA = lA + srow * PAD_ROW + scg * 16;
    short* wpB = lB + srow * PAD_ROW + scg * 16;
    const short* rpA = lA + (wr * 64 + r15) * PAD_ROW + kg * 8;
    const short* rpB = lB + (wc * 64 + r15) * PAD_ROW + kg * 8;
    f32x4 acc[4][4];
    #pragma unroll
    for (int i = 0; i < 4; ++i)
        #pragma unroll
        for (int j = 0; j < 4; ++j) acc[i][j] = (f32x4){0.f, 0.f, 0.f, 0.f};
    for (int t = 0; t < K_TOT / 32; ++t) {
        const int r = t >> 5, k0 = (t & 31) << 5;
        const float* pA = gA + (size_t)r * (M_TOT * LK) + k0;
        const float* pB = gB + (size_t)r * (N_TOT * LK) + k0;
        f32x4 va[4], vb[4];
        #pragma unroll
        for (int q = 0; q < 4; ++q) va[q] = *(const f32x4*)(pA + q * 4);
        #pragma unroll
        for (int q = 0; q < 4; ++q) vb[q] = *(const f32x4*)(pB + q * 4);
        __syncthreads();
        s16x8 oa0, oa1, ob0, ob1;
        #pragma unroll
        for (int q = 0; q < 2; ++q)
            #pragma unroll
            for (int i = 0; i < 4; ++i) {
                oa0[q * 4 + i] = f2bf(va[q][i]);
                oa1[q * 4 + i] = f2bf(va[q + 2][i]);
                ob0[q * 4 + i] = f2bf(vb[q][i]);
                ob1[q * 4 + i] = f2bf(vb[q + 2][i]);
            }
        *(s16x8*)(wpA) = oa0; *(s16x8*)(wpA + 8) = oa1;
        *(s16x8*)(wpB) = ob0; *(s16x8*)(wpB + 8) = ob1;
        __syncthreads();
        s16x8 af[4], bfr2[4];
        #pragma unroll
        for (int i = 0; i < 4; ++i) af[i]   = *(const s16x8*)(rpA + i * 16 * PAD_ROW);
        #pragma unroll
        for (int i = 0; i < 4; ++i) bfr2[i] = *(const s16x8*)(rpB + i * 16 * PAD_ROW);
        #pragma unroll
        for (int i = 0; i < 4; ++i)
            #pragma unroll
            for (int j = 0; j < 4; ++j)
                acc[i][j] = __builtin_amdgcn_mfma_f32_16x16x32_bf16(
                    af[i], bfr2[j], acc[i][j], 0, 0, 0);
    }
    float* Cp = C + (size_t)(bm * 128 + wr * 64 + kg * 4) * N_TOT
                  + bn * 128 + wc * 64 + r15;
    #pragma unroll
    for (int i = 0; i < 4; ++i)
        #pragma unroll
        for (int j = 0; j < 4; ++j)
            #pragma unroll
            for (int jj = 0; jj < 4; ++jj)
                Cp[(size_t)(i * 16 + jj) * N_TOT + j * 16] = acc[i][j][jj];
}

extern "C" void kernel_launch(void* const* d_in, const int* in_sizes, int n_in,
                              void* d_out, int out_size, void* d_ws, size_t ws_size,
                              hipStream_t stream) {
    const float* A = (const float*)d_in[0];   // [8, 8192, 1024]
    const float* B = (const float*)d_in[1];   // [8, 4096, 1024]
    float* C = (float*)d_out;                 // [8192, 4096]

    const size_t needA = (size_t)M_TOT * K_TOT * 2;
    const size_t needB = (size_t)N_TOT * K_TOT * 2;

    if (ws_size >= needA + needB) {
        short* Abf = (short*)d_ws;
        short* Bbf = (short*)((char*)d_ws + needA);
        cvt_bf16<<<dim3(NR * M_TOT / 2), dim3(256), 0, stream>>>(A, Abf, 13, 8191);
        cvt_bf16<<<dim3(NR * N_TOT / 2), dim3(256), 0, stream>>>(B, Bbf, 12, 4095);
        gemm8<<<dim3((M_TOT / 256) * (N_TOT / 256)), dim3(512), 131072, stream>>>(Abf, Bbf, C);
    } else {
        gemm_rs_fused<<<dim3((M_TOT / 128) * (N_TOT / 128)), dim3(256), 0, stream>>>(A, B, C);
    }
}